// Round 6
// baseline (543.877 us; speedup 1.0000x reference)
//
#include <hip/hip_runtime.h>
#include <math.h>

#define DEV static __device__ __forceinline__

// ---------------- 4-qubit real-amplitude circuit helpers ----------------
template <int W>
DEV void q_ry(float s[16], float th) {
  float c = cosf(th * 0.5f), sn = sinf(th * 0.5f);
  constexpr int m = 8 >> W;
#pragma unroll
  for (int i = 0; i < 16; ++i) {
    if (!(i & m)) {
      float a = s[i], b = s[i | m];
      s[i] = c * a - sn * b;
      s[i | m] = sn * a + c * b;
    }
  }
}
template <int C, int T>
DEV void q_cnot(float s[16]) {
  constexpr int mc = 8 >> C, mt = 8 >> T;
#pragma unroll
  for (int i = 0; i < 16; ++i) {
    if ((i & mc) && !(i & mt)) {
      float t = s[i]; s[i] = s[i | mt]; s[i | mt] = t;
    }
  }
}
template <int W>
DEV float q_mz(const float s[16]) {
  constexpr int m = 8 >> W;
  float p = 0.f;
#pragma unroll
  for (int i = 0; i < 16; ++i) p += (i & m) ? -s[i] * s[i] : s[i] * s[i];
  return p;
}
DEV void q_layer(float s[16], const float* __restrict__ th) {
  q_ry<0>(s, th[0]); q_cnot<0, 1>(s);
  q_ry<1>(s, th[1]); q_cnot<1, 2>(s);
  q_ry<2>(s, th[2]); q_cnot<2, 3>(s);
  q_ry<3>(s, th[3]); q_cnot<3, 0>(s);
}

// ---------------- conv1 (5x5 s2 p1, 3->6) + relu + pool(2x2 s1) ----------------
// Block = 32x32 pooled tile. Thread = 2x2 pooled quad (own 3x3 conv patch in
// registers, in-register pooling). Channels in 2 groups of 3. All 256 threads
// active; weights and inputs hit registers once per 135-FMA sweep.
// x: (128,3,249,249) -> pooled out: (128,6,123,123)
__global__ __launch_bounds__(256) void k_conv1(const float* __restrict__ x,
                                               const float* __restrict__ w,
                                               const float* __restrict__ bia,
                                               float* __restrict__ out) {
  __shared__ float xs[3][69][69];   // input tile (span = 32*2+5)
  __shared__ float wt[480];         // [ci][ky][g][16] padded, [co-in-g][kx] inside
  int b = blockIdx.z;
  int PY0 = blockIdx.y * 32, PX0 = blockIdx.x * 32;
  int iy0 = PY0 * 2 - 1, ix0 = PX0 * 2 - 1;
  int tid = threadIdx.x;
  for (int i = tid; i < 480; i += 256) {
    int ci = i / 160, ky = (i / 32) % 5, g = (i / 16) % 2, t = i % 16;
    wt[i] = (t < 15) ? w[(g * 3 + t / 5) * 75 + ci * 25 + ky * 5 + (t % 5)] : 0.f;
  }
  const float* xb = x + (size_t)b * 186003;  // 3*249*249
  for (int idx = tid; idx < 3 * 69 * 69; idx += 256) {
    int ci = idx / 4761, r = (idx % 4761) / 69, cc = idx % 69;
    int iy = iy0 + r, ix = ix0 + cc;
    float v = 0.f;
    if (iy >= 0 && iy < 249 && ix >= 0 && ix < 249)
      v = xb[ci * 62001 + iy * 249 + ix];
    xs[ci][r][cc] = v;
  }
  __syncthreads();
  int ty = tid >> 4, tx = tid & 15;
  int rbase = 4 * ty, cbase = 4 * tx;
#pragma unroll
  for (int g = 0; g < 2; ++g) {
    float acc[3][3][3];  // [j][conv-row][conv-col]
#pragma unroll
    for (int j = 0; j < 3; ++j) {
      float bv = bia[g * 3 + j];
#pragma unroll
      for (int cr = 0; cr < 3; ++cr)
#pragma unroll
        for (int cc = 0; cc < 3; ++cc) acc[j][cr][cc] = bv;
    }
    for (int ci = 0; ci < 3; ++ci) {
#pragma unroll
      for (int ky = 0; ky < 5; ++ky) {
        float xv[3][9];
#pragma unroll
        for (int cr = 0; cr < 3; ++cr)
#pragma unroll
          for (int c = 0; c < 9; ++c)
            xv[cr][c] = xs[ci][rbase + ky + 2 * cr][cbase + c];
        const float* wp = &wt[(ci * 5 + ky) * 32 + g * 16];
        float wr[15];
#pragma unroll
        for (int t2 = 0; t2 < 15; ++t2) wr[t2] = wp[t2];
#pragma unroll
        for (int j = 0; j < 3; ++j)
#pragma unroll
          for (int cr = 0; cr < 3; ++cr)
#pragma unroll
            for (int cc = 0; cc < 3; ++cc)
#pragma unroll
              for (int kx = 0; kx < 5; ++kx)
                acc[j][cr][cc] += xv[cr][2 * cc + kx] * wr[j * 5 + kx];
      }
    }
#pragma unroll
    for (int j = 0; j < 3; ++j) {
      int co = g * 3 + j;
#pragma unroll
      for (int pr = 0; pr < 2; ++pr)
#pragma unroll
        for (int pc = 0; pc < 2; ++pc) {
          int py = PY0 + 2 * ty + pr, px = PX0 + 2 * tx + pc;
          if (py < 123 && px < 123) {
            float m = fmaxf(fmaxf(acc[j][pr][pc], acc[j][pr][pc + 1]),
                            fmaxf(acc[j][pr + 1][pc], acc[j][pr + 1][pc + 1]));
            out[((size_t)(b * 6 + co) * 123 + py) * 123 + px] = fmaxf(m, 0.f);
          }
        }
    }
  }
}

// ---------------- conv2 (3x3 s2 p1, 6->15) + relu + pool ----------------
// in: (128,6,123,123) -> h: (128, 15*61*61=55815) flattened
__global__ __launch_bounds__(256) void k_conv2(const float* __restrict__ in,
                                               const float* __restrict__ w,
                                               const float* __restrict__ bia,
                                               float* __restrict__ out) {
  __shared__ float xs[6][35][35];   // span = 16*2+3
  __shared__ float wt[54 * 15];     // transposed weights [j][co]
  __shared__ float ct[15][17][18];
  int b = blockIdx.z;
  int py0 = blockIdx.y * 16, px0 = blockIdx.x * 16;
  int iy0 = py0 * 2 - 1, ix0 = px0 * 2 - 1;
  int tid = threadIdx.x;
  for (int i = tid; i < 810; i += 256) {
    int j = i / 15, co = i % 15;
    wt[i] = w[co * 54 + j];
  }
  const float* ib = in + (size_t)b * 90774;  // 6*123*123
  for (int idx = tid; idx < 6 * 35 * 35; idx += 256) {
    int ci = idx / 1225, r = (idx % 1225) / 35, cc = idx % 35;
    int iy = iy0 + r, ix = ix0 + cc;
    float v = 0.f;
    if (iy >= 0 && iy < 123 && ix >= 0 && ix < 123)
      v = ib[ci * 15129 + iy * 123 + ix];
    xs[ci][r][cc] = v;
  }
  __syncthreads();
  if (tid < 255) {                 // 15 co * 17 rows
    int co = tid % 15, ty = tid / 15;
    float acc[17];
    float bv = bia[co];
#pragma unroll
    for (int t = 0; t < 17; ++t) acc[t] = bv;
#pragma unroll
    for (int ci = 0; ci < 6; ++ci)
#pragma unroll
      for (int ky = 0; ky < 3; ++ky) {
        int y = ty * 2 + ky;
        const int jb = (ci * 9 + ky * 3) * 15 + co;
        float w0 = wt[jb], w1 = wt[jb + 15], w2 = wt[jb + 30];
        float xp = xs[ci][y][0];
#pragma unroll
        for (int tx = 0; tx < 17; ++tx) {
          float xa = xs[ci][y][2 * tx + 1];
          float xb2 = xs[ci][y][2 * tx + 2];
          acc[tx] += xp * w0 + xa * w1 + xb2 * w2;
          xp = xb2;
        }
      }
#pragma unroll
    for (int tx = 0; tx < 17; ++tx) ct[co][ty][tx] = acc[tx];
  }
  __syncthreads();
  if (tid < 240) {                 // 15 co * 16 pooled rows
    int co = tid % 15, ty = tid / 15;
    int py = py0 + ty;
    if (py < 61) {
      float* op = out + (size_t)b * 55815 + co * 3721 + py * 61 + px0;
#pragma unroll
      for (int tx = 0; tx < 16; ++tx) {
        if (px0 + tx < 61) {
          float m = fmaxf(fmaxf(ct[co][ty][tx], ct[co][ty][tx + 1]),
                          fmaxf(ct[co][ty + 1][tx], ct[co][ty + 1][tx + 1]));
          op[tx] = fmaxf(m, 0.f);
        }
      }
    }
  }
}

// ---------------- fc1: (128,55815) x (120,55815)^T, split-K partials ----------------
#define KFC 55815
#define NCHUNK 1745  // ceil(55815/32)
__global__ __launch_bounds__(256) void k_fc1(const float* __restrict__ h,
                                             const float* __restrict__ w,
                                             float* __restrict__ partial) {
  __shared__ float hs[128][33];   // +1 pad
  __shared__ float wsd[120][33];
  int tid = threadIdx.x;
  int tb = tid & 31;   // batch lane
  int bo = tid >> 5;   // output group: outputs bo*15 .. bo*15+14
  float acc[4][15];
#pragma unroll
  for (int j = 0; j < 4; ++j)
#pragma unroll
    for (int oo = 0; oo < 15; ++oo) acc[j][oo] = 0.f;

  for (int ch = blockIdx.x; ch < NCHUNK; ch += gridDim.x) {
    int k0 = ch * 32;
    for (int idx = tid; idx < 128 * 32; idx += 256) {
      int bb = idx >> 5, kk = idx & 31;
      int k = k0 + kk;
      hs[bb][kk] = (k < KFC) ? h[(size_t)bb * KFC + k] : 0.f;
    }
    for (int idx = tid; idx < 120 * 32; idx += 256) {
      int oo = idx >> 5, kk = idx & 31;
      int k = k0 + kk;
      wsd[oo][kk] = (k < KFC) ? w[(size_t)oo * KFC + k] : 0.f;
    }
    __syncthreads();
#pragma unroll 4
    for (int kk = 0; kk < 32; ++kk) {
      float hv[4], wv[15];
#pragma unroll
      for (int j = 0; j < 4; ++j) hv[j] = hs[tb + 32 * j][kk];
#pragma unroll
      for (int oo = 0; oo < 15; ++oo) wv[oo] = wsd[bo * 15 + oo][kk];
#pragma unroll
      for (int j = 0; j < 4; ++j)
#pragma unroll
        for (int oo = 0; oo < 15; ++oo) acc[j][oo] += hv[j] * wv[oo];
    }
    __syncthreads();
  }
  float* pg = partial + (size_t)blockIdx.x * 15360;
#pragma unroll
  for (int j = 0; j < 4; ++j) {
    int b = tb + 32 * j;
#pragma unroll
    for (int oo = 0; oo < 15; ++oo) pg[b * 120 + bo * 15 + oo] = acc[j][oo];
  }
}

__global__ __launch_bounds__(256) void k_fc1_reduce(const float* __restrict__ partial,
                                                    const float* __restrict__ bias,
                                                    float* __restrict__ outv) {
  int i = blockIdx.x * 256 + threadIdx.x;
  if (i >= 15360) return;
  float a = bias[i % 120];
  for (int g = 0; g < 256; ++g) a += partial[(size_t)g * 15360 + i];
  outv[i] = fmaxf(a, 0.f);  // relu fused
}

// ---------------- fc2 + fc3 + quantum head -> probs_conv ----------------
__global__ __launch_bounds__(128) void k_head(const float* __restrict__ fc1o,
                                              const float* __restrict__ w2,
                                              const float* __restrict__ b2,
                                              const float* __restrict__ w3,
                                              const float* __restrict__ b3,
                                              const float* __restrict__ hth,
                                              float* __restrict__ probs_conv) {
  __shared__ float h1[120];
  __shared__ float h2[84];
  int b = blockIdx.x, tid = threadIdx.x;
  if (tid < 120) h1[tid] = fc1o[b * 120 + tid];  // already relu'd
  __syncthreads();
  if (tid < 84) {
    float a = b2[tid];
    for (int k = 0; k < 120; ++k) a += h1[k] * w2[tid * 120 + k];
    h2[tid] = fmaxf(a, 0.f);
  }
  __syncthreads();
  if (tid == 0) {
    float lg = b3[0];
    for (int j = 0; j < 84; ++j) lg += h2[j] * w3[j];
    float s[16];
#pragma unroll
    for (int i = 0; i < 16; ++i) s[i] = 0.f;
    s[0] = 1.f;
    q_ry<0>(s, lg);
    q_layer(s, hth);
    float z = q_mz<0>(s);
    probs_conv[b] = 1.f / (1.f + expf(-z));
  }
}

// ---------------- resize 249->28 (jax linear+antialias), row pass ----------------
DEV void resize_win(int o, int& i0, int& i1, float& sf, float& inorm) {
  const float invs = 249.0f / 28.0f;
  sf = ((float)o + 0.5f) * invs - 0.5f;
  i0 = (int)ceilf(sf - invs); if (i0 < 0) i0 = 0;
  i1 = (int)floorf(sf + invs); if (i1 > 248) i1 = 248;
  float nrm = 0.f;
  for (int i = i0; i <= i1; ++i)
    nrm += fmaxf(0.f, 1.f - fabsf(sf - (float)i) * (28.0f / 249.0f));
  inorm = 1.f / nrm;
}

// tmp[b][oy][ix] = sum_iy W[oy][iy] * gray[b][iy][ix]
__global__ __launch_bounds__(256) void k_resize_rows(const float* __restrict__ x,
                                                     float* __restrict__ tmp) {
  int b = blockIdx.x / 28, oy = blockIdx.x % 28;
  int ix = threadIdx.x;
  if (ix >= 249) return;
  int i0, i1; float sf, inorm;
  resize_win(oy, i0, i1, sf, inorm);
  const float* xb = x + (size_t)b * 186003;
  float acc = 0.f;
  for (int iy = i0; iy <= i1; ++iy) {
    float wv = fmaxf(0.f, 1.f - fabsf(sf - (float)iy) * (28.0f / 249.0f)) * inorm;
    float gr = (xb[iy * 249 + ix] + xb[62001 + iy * 249 + ix] +
                xb[124002 + iy * 249 + ix]) * (1.0f / 3.0f);
    acc += wv * gr;
  }
  tmp[((size_t)b * 28 + oy) * 249 + ix] = acc;
}

// ---------------- col pass + patches + per-patch circuits + lin + combine ----------------
__global__ __launch_bounds__(256) void k_quanv(const float* __restrict__ tmp,
                                               const float* __restrict__ qth,
                                               const float* __restrict__ lw,
                                               const float* __restrict__ lb,
                                               const float* __restrict__ probs_conv,
                                               float* __restrict__ out) {
  __shared__ float g[784];
  __shared__ float red[4];
  int b = blockIdx.x, tid = threadIdx.x;
  for (int idx = tid; idx < 784; idx += 256) {
    int oy = idx / 28, ox = idx % 28;
    int i0, i1; float sf, inorm;
    resize_win(ox, i0, i1, sf, inorm);
    const float* tr = tmp + ((size_t)b * 28 + oy) * 249;
    float acc = 0.f;
    for (int i = i0; i <= i1; ++i)
      acc += fmaxf(0.f, 1.f - fabsf(sf - (float)i) * (28.0f / 249.0f)) * inorm * tr[i];
    g[idx] = acc;
  }
  __syncthreads();
  float part = 0.f;
  if (tid < 196) {
    int pi = tid / 14, pj = tid % 14;
    float v0 = g[(2 * pi) * 28 + 2 * pj];
    float v1 = g[(2 * pi) * 28 + 2 * pj + 1];
    float v2 = g[(2 * pi + 1) * 28 + 2 * pj];
    float v3 = g[(2 * pi + 1) * 28 + 2 * pj + 1];
    float s[16];
#pragma unroll
    for (int i = 0; i < 16; ++i) s[i] = 0.f;
    s[0] = 1.f;
    q_ry<0>(s, v0); q_ry<1>(s, v1); q_ry<2>(s, v2); q_ry<3>(s, v3);
    q_layer(s, qth);
    float z0 = q_mz<0>(s), z1 = q_mz<1>(s), z2 = q_mz<2>(s), z3 = q_mz<3>(s);
    const float* lwp = lw + tid * 4;
    part = z0 * lwp[0] + z1 * lwp[1] + z2 * lwp[2] + z3 * lwp[3];
  }
#pragma unroll
  for (int off = 32; off > 0; off >>= 1) part += __shfl_down(part, off, 64);
  if ((tid & 63) == 0) red[tid >> 6] = part;
  __syncthreads();
  if (tid == 0) {
    float tot = red[0] + red[1] + red[2] + red[3] + lb[0];
    float pq = 1.f / (1.f + expf(-tot));
    float pr = 0.5f * (probs_conv[b] + pq);
    out[b * 2 + 0] = pr;
    out[b * 2 + 1] = 1.f - pr;
  }
}

// ---------------- launch ----------------
extern "C" void kernel_launch(void* const* d_in, const int* in_sizes, int n_in,
                              void* d_out, int out_size, void* d_ws, size_t ws_size,
                              hipStream_t stream) {
  const float* x   = (const float*)d_in[0];
  const float* c1w = (const float*)d_in[1];
  const float* c1b = (const float*)d_in[2];
  const float* c2w = (const float*)d_in[3];
  const float* c2b = (const float*)d_in[4];
  const float* f1w = (const float*)d_in[5];
  const float* f1b = (const float*)d_in[6];
  const float* f2w = (const float*)d_in[7];
  const float* f2b = (const float*)d_in[8];
  const float* f3w = (const float*)d_in[9];
  const float* f3b = (const float*)d_in[10];
  const float* hth = (const float*)d_in[11];
  const float* qth = (const float*)d_in[12];
  const float* lw  = (const float*)d_in[13];
  const float* lb  = (const float*)d_in[14];
  float* out = (float*)d_out;
  char* ws = (char*)d_ws;

  float* pool1   = (float*)(ws);
  float* partial = pool1;  // pool1 dead after k_conv2
  float* h       = (float*)(ws + 46476288);
  float* tmp     = (float*)(ws + 75053568);
  float* fc1o    = (float*)(ws + 78623232);
  float* pconv   = (float*)(ws + 78684672);

  k_conv1<<<dim3(4, 4, 128), 256, 0, stream>>>(x, c1w, c1b, pool1);
  k_conv2<<<dim3(4, 4, 128), 256, 0, stream>>>(pool1, c2w, c2b, h);
  k_fc1<<<dim3(256), 256, 0, stream>>>(h, f1w, partial);
  k_fc1_reduce<<<dim3(60), 256, 0, stream>>>(partial, f1b, fc1o);
  k_head<<<dim3(128), 128, 0, stream>>>(fc1o, f2w, f2b, f3w, f3b, hth, pconv);
  k_resize_rows<<<dim3(128 * 28), 256, 0, stream>>>(x, tmp);
  k_quanv<<<dim3(128), 256, 0, stream>>>(tmp, qth, lw, lb, pconv, out);
}

// Round 7
// 417.191 us; speedup vs baseline: 1.3037x; 1.3037x over previous
//
#include <hip/hip_runtime.h>
#include <math.h>

#define DEV static __device__ __forceinline__

// ---------------- 4-qubit real-amplitude circuit helpers ----------------
template <int W>
DEV void q_ry(float s[16], float th) {
  float c = cosf(th * 0.5f), sn = sinf(th * 0.5f);
  constexpr int m = 8 >> W;
#pragma unroll
  for (int i = 0; i < 16; ++i) {
    if (!(i & m)) {
      float a = s[i], b = s[i | m];
      s[i] = c * a - sn * b;
      s[i | m] = sn * a + c * b;
    }
  }
}
template <int C, int T>
DEV void q_cnot(float s[16]) {
  constexpr int mc = 8 >> C, mt = 8 >> T;
#pragma unroll
  for (int i = 0; i < 16; ++i) {
    if ((i & mc) && !(i & mt)) {
      float t = s[i]; s[i] = s[i | mt]; s[i | mt] = t;
    }
  }
}
template <int W>
DEV float q_mz(const float s[16]) {
  constexpr int m = 8 >> W;
  float p = 0.f;
#pragma unroll
  for (int i = 0; i < 16; ++i) p += (i & m) ? -s[i] * s[i] : s[i] * s[i];
  return p;
}
DEV void q_layer(float s[16], const float* __restrict__ th) {
  q_ry<0>(s, th[0]); q_cnot<0, 1>(s);
  q_ry<1>(s, th[1]); q_cnot<1, 2>(s);
  q_ry<2>(s, th[2]); q_cnot<2, 3>(s);
  q_ry<3>(s, th[3]); q_cnot<3, 0>(s);
}

// ---------------- conv1 (5x5 s2 p1, 3->6) + relu + pool(2x2 s1) ----------------
// Strip-mined like conv2 (which benches well): thread = (co, conv-row),
// 17-output sliding sweep, weights in regs (25 at a time, per-ci).
// Geometry fixed for utilization: 6 co * 42 rows = 252/256 threads,
// tile = 41x16 pooled (123 = 3*41 exactly).
// x: (128,3,249,249) -> pooled out: (128,6,123,123)
__global__ __launch_bounds__(256) void k_conv1(const float* __restrict__ x,
                                               const float* __restrict__ w,
                                               const float* __restrict__ bia,
                                               float* __restrict__ out) {
  __shared__ float xs[3][87][37];   // rows span 42*2+3, cols 16*2+5
  __shared__ float ct[6][42][18];   // conv subtile (+1 col pad)
  int b = blockIdx.z;
  int PY0 = blockIdx.y * 41, PX0 = blockIdx.x * 16;
  int iy0 = PY0 * 2 - 1, ix0 = PX0 * 2 - 1;
  int tid = threadIdx.x;
  const float* xb = x + (size_t)b * 186003;  // 3*249*249
  for (int idx = tid; idx < 3 * 87 * 37; idx += 256) {
    int ci = idx / 3219, rem = idx % 3219, rr = rem / 37, cc = rem % 37;
    int iy = iy0 + rr, ix = ix0 + cc;
    float v = 0.f;
    if (iy >= 0 && iy < 249 && ix >= 0 && ix < 249)
      v = xb[ci * 62001 + iy * 249 + ix];
    xs[ci][rr][cc] = v;
  }
  __syncthreads();
  int co = tid / 42, r = tid % 42;
  if (tid < 252) {
    float acc[17];
    float bv = bia[co];
#pragma unroll
    for (int t = 0; t < 17; ++t) acc[t] = bv;
    for (int ci = 0; ci < 3; ++ci) {
      float wreg[25];                       // this co, this ci: 5x5
#pragma unroll
      for (int j = 0; j < 25; ++j) wreg[j] = w[co * 75 + ci * 25 + j];
#pragma unroll
      for (int ky = 0; ky < 5; ++ky) {
        const float* xrow = &xs[ci][2 * r + ky][0];
#pragma unroll
        for (int tx = 0; tx < 17; ++tx)
#pragma unroll
          for (int kx = 0; kx < 5; ++kx)
            acc[tx] += xrow[2 * tx + kx] * wreg[ky * 5 + kx];
      }
    }
#pragma unroll
    for (int tx = 0; tx < 17; ++tx) ct[co][r][tx] = acc[tx];
  }
  __syncthreads();
  if (tid < 246) {                  // 6 co * 41 pooled rows
    int co2 = tid / 41, pr = tid % 41;
    int py = PY0 + pr;              // always < 123 (3*41=123)
    float* op = out + ((size_t)(b * 6 + co2) * 123 + py) * 123 + PX0;
#pragma unroll
    for (int pc = 0; pc < 16; ++pc) {
      if (PX0 + pc < 123) {
        float m = fmaxf(fmaxf(ct[co2][pr][pc], ct[co2][pr][pc + 1]),
                        fmaxf(ct[co2][pr + 1][pc], ct[co2][pr + 1][pc + 1]));
        op[pc] = fmaxf(m, 0.f);
      }
    }
  }
}

// ---------------- conv2 (3x3 s2 p1, 6->15) + relu + pool ----------------
// in: (128,6,123,123) -> h: (128, 15*61*61=55815) flattened
__global__ __launch_bounds__(256) void k_conv2(const float* __restrict__ in,
                                               const float* __restrict__ w,
                                               const float* __restrict__ bia,
                                               float* __restrict__ out) {
  __shared__ float xs[6][35][35];   // span = 16*2+3
  __shared__ float wt[54 * 15];     // transposed weights [j][co]
  __shared__ float ct[15][17][18];
  int b = blockIdx.z;
  int py0 = blockIdx.y * 16, px0 = blockIdx.x * 16;
  int iy0 = py0 * 2 - 1, ix0 = px0 * 2 - 1;
  int tid = threadIdx.x;
  for (int i = tid; i < 810; i += 256) {
    int j = i / 15, co = i % 15;
    wt[i] = w[co * 54 + j];
  }
  const float* ib = in + (size_t)b * 90774;  // 6*123*123
  for (int idx = tid; idx < 6 * 35 * 35; idx += 256) {
    int ci = idx / 1225, r = (idx % 1225) / 35, cc = idx % 35;
    int iy = iy0 + r, ix = ix0 + cc;
    float v = 0.f;
    if (iy >= 0 && iy < 123 && ix >= 0 && ix < 123)
      v = ib[ci * 15129 + iy * 123 + ix];
    xs[ci][r][cc] = v;
  }
  __syncthreads();
  if (tid < 255) {                 // 15 co * 17 rows
    int co = tid % 15, ty = tid / 15;
    float acc[17];
    float bv = bia[co];
#pragma unroll
    for (int t = 0; t < 17; ++t) acc[t] = bv;
#pragma unroll
    for (int ci = 0; ci < 6; ++ci)
#pragma unroll
      for (int ky = 0; ky < 3; ++ky) {
        int y = ty * 2 + ky;
        const int jb = (ci * 9 + ky * 3) * 15 + co;
        float w0 = wt[jb], w1 = wt[jb + 15], w2 = wt[jb + 30];
        float xp = xs[ci][y][0];
#pragma unroll
        for (int tx = 0; tx < 17; ++tx) {
          float xa = xs[ci][y][2 * tx + 1];
          float xb2 = xs[ci][y][2 * tx + 2];
          acc[tx] += xp * w0 + xa * w1 + xb2 * w2;
          xp = xb2;
        }
      }
#pragma unroll
    for (int tx = 0; tx < 17; ++tx) ct[co][ty][tx] = acc[tx];
  }
  __syncthreads();
  if (tid < 240) {                 // 15 co * 16 pooled rows
    int co = tid % 15, ty = tid / 15;
    int py = py0 + ty;
    if (py < 61) {
      float* op = out + (size_t)b * 55815 + co * 3721 + py * 61 + px0;
#pragma unroll
      for (int tx = 0; tx < 16; ++tx) {
        if (px0 + tx < 61) {
          float m = fmaxf(fmaxf(ct[co][ty][tx], ct[co][ty][tx + 1]),
                          fmaxf(ct[co][ty + 1][tx], ct[co][ty + 1][tx + 1]));
          op[tx] = fmaxf(m, 0.f);
        }
      }
    }
  }
}

// ---------------- fc1: (128,55815) x (120,55815)^T, split-K partials ----------------
#define KFC 55815
#define NCHUNK 1745  // ceil(55815/32)
__global__ __launch_bounds__(256) void k_fc1(const float* __restrict__ h,
                                             const float* __restrict__ w,
                                             float* __restrict__ partial) {
  __shared__ float hs[128][33];   // +1 pad
  __shared__ float wsd[120][33];
  int tid = threadIdx.x;
  int tb = tid & 31;   // batch lane
  int bo = tid >> 5;   // output group: outputs bo*15 .. bo*15+14
  float acc[4][15];
#pragma unroll
  for (int j = 0; j < 4; ++j)
#pragma unroll
    for (int oo = 0; oo < 15; ++oo) acc[j][oo] = 0.f;

  for (int ch = blockIdx.x; ch < NCHUNK; ch += gridDim.x) {
    int k0 = ch * 32;
    for (int idx = tid; idx < 128 * 32; idx += 256) {
      int bb = idx >> 5, kk = idx & 31;
      int k = k0 + kk;
      hs[bb][kk] = (k < KFC) ? h[(size_t)bb * KFC + k] : 0.f;
    }
    for (int idx = tid; idx < 120 * 32; idx += 256) {
      int oo = idx >> 5, kk = idx & 31;
      int k = k0 + kk;
      wsd[oo][kk] = (k < KFC) ? w[(size_t)oo * KFC + k] : 0.f;
    }
    __syncthreads();
#pragma unroll 4
    for (int kk = 0; kk < 32; ++kk) {
      float hv[4], wv[15];
#pragma unroll
      for (int j = 0; j < 4; ++j) hv[j] = hs[tb + 32 * j][kk];
#pragma unroll
      for (int oo = 0; oo < 15; ++oo) wv[oo] = wsd[bo * 15 + oo][kk];
#pragma unroll
      for (int j = 0; j < 4; ++j)
#pragma unroll
        for (int oo = 0; oo < 15; ++oo) acc[j][oo] += hv[j] * wv[oo];
    }
    __syncthreads();
  }
  float* pg = partial + (size_t)blockIdx.x * 15360;
#pragma unroll
  for (int j = 0; j < 4; ++j) {
    int b = tb + 32 * j;
#pragma unroll
    for (int oo = 0; oo < 15; ++oo) pg[b * 120 + bo * 15 + oo] = acc[j][oo];
  }
}

__global__ __launch_bounds__(256) void k_fc1_reduce(const float* __restrict__ partial,
                                                    const float* __restrict__ bias,
                                                    float* __restrict__ outv) {
  int i = blockIdx.x * 256 + threadIdx.x;
  if (i >= 15360) return;
  float a = bias[i % 120];
  for (int g = 0; g < 256; ++g) a += partial[(size_t)g * 15360 + i];
  outv[i] = fmaxf(a, 0.f);  // relu fused
}

// ---------------- fc2 + fc3 + quantum head -> probs_conv ----------------
__global__ __launch_bounds__(128) void k_head(const float* __restrict__ fc1o,
                                              const float* __restrict__ w2,
                                              const float* __restrict__ b2,
                                              const float* __restrict__ w3,
                                              const float* __restrict__ b3,
                                              const float* __restrict__ hth,
                                              float* __restrict__ probs_conv) {
  __shared__ float h1[120];
  __shared__ float h2[84];
  int b = blockIdx.x, tid = threadIdx.x;
  if (tid < 120) h1[tid] = fc1o[b * 120 + tid];  // already relu'd
  __syncthreads();
  if (tid < 84) {
    float a = b2[tid];
    for (int k = 0; k < 120; ++k) a += h1[k] * w2[tid * 120 + k];
    h2[tid] = fmaxf(a, 0.f);
  }
  __syncthreads();
  if (tid == 0) {
    float lg = b3[0];
    for (int j = 0; j < 84; ++j) lg += h2[j] * w3[j];
    float s[16];
#pragma unroll
    for (int i = 0; i < 16; ++i) s[i] = 0.f;
    s[0] = 1.f;
    q_ry<0>(s, lg);
    q_layer(s, hth);
    float z = q_mz<0>(s);
    probs_conv[b] = 1.f / (1.f + expf(-z));
  }
}

// ---------------- resize 249->28 (jax linear+antialias), row pass ----------------
DEV void resize_win(int o, int& i0, int& i1, float& sf, float& inorm) {
  const float invs = 249.0f / 28.0f;
  sf = ((float)o + 0.5f) * invs - 0.5f;
  i0 = (int)ceilf(sf - invs); if (i0 < 0) i0 = 0;
  i1 = (int)floorf(sf + invs); if (i1 > 248) i1 = 248;
  float nrm = 0.f;
  for (int i = i0; i <= i1; ++i)
    nrm += fmaxf(0.f, 1.f - fabsf(sf - (float)i) * (28.0f / 249.0f));
  inorm = 1.f / nrm;
}

// tmp[b][oy][ix] = sum_iy W[oy][iy] * gray[b][iy][ix]
__global__ __launch_bounds__(256) void k_resize_rows(const float* __restrict__ x,
                                                     float* __restrict__ tmp) {
  int b = blockIdx.x / 28, oy = blockIdx.x % 28;
  int ix = threadIdx.x;
  if (ix >= 249) return;
  int i0, i1; float sf, inorm;
  resize_win(oy, i0, i1, sf, inorm);
  const float* xb = x + (size_t)b * 186003;
  float acc = 0.f;
  for (int iy = i0; iy <= i1; ++iy) {
    float wv = fmaxf(0.f, 1.f - fabsf(sf - (float)iy) * (28.0f / 249.0f)) * inorm;
    float gr = (xb[iy * 249 + ix] + xb[62001 + iy * 249 + ix] +
                xb[124002 + iy * 249 + ix]) * (1.0f / 3.0f);
    acc += wv * gr;
  }
  tmp[((size_t)b * 28 + oy) * 249 + ix] = acc;
}

// ---------------- col pass + patches + per-patch circuits + lin + combine ----------------
__global__ __launch_bounds__(256) void k_quanv(const float* __restrict__ tmp,
                                               const float* __restrict__ qth,
                                               const float* __restrict__ lw,
                                               const float* __restrict__ lb,
                                               const float* __restrict__ probs_conv,
                                               float* __restrict__ out) {
  __shared__ float g[784];
  __shared__ float red[4];
  int b = blockIdx.x, tid = threadIdx.x;
  for (int idx = tid; idx < 784; idx += 256) {
    int oy = idx / 28, ox = idx % 28;
    int i0, i1; float sf, inorm;
    resize_win(ox, i0, i1, sf, inorm);
    const float* tr = tmp + ((size_t)b * 28 + oy) * 249;
    float acc = 0.f;
    for (int i = i0; i <= i1; ++i)
      acc += fmaxf(0.f, 1.f - fabsf(sf - (float)i) * (28.0f / 249.0f)) * inorm * tr[i];
    g[idx] = acc;
  }
  __syncthreads();
  float part = 0.f;
  if (tid < 196) {
    int pi = tid / 14, pj = tid % 14;
    float v0 = g[(2 * pi) * 28 + 2 * pj];
    float v1 = g[(2 * pi) * 28 + 2 * pj + 1];
    float v2 = g[(2 * pi + 1) * 28 + 2 * pj];
    float v3 = g[(2 * pi + 1) * 28 + 2 * pj + 1];
    float s[16];
#pragma unroll
    for (int i = 0; i < 16; ++i) s[i] = 0.f;
    s[0] = 1.f;
    q_ry<0>(s, v0); q_ry<1>(s, v1); q_ry<2>(s, v2); q_ry<3>(s, v3);
    q_layer(s, qth);
    float z0 = q_mz<0>(s), z1 = q_mz<1>(s), z2 = q_mz<2>(s), z3 = q_mz<3>(s);
    const float* lwp = lw + tid * 4;
    part = z0 * lwp[0] + z1 * lwp[1] + z2 * lwp[2] + z3 * lwp[3];
  }
#pragma unroll
  for (int off = 32; off > 0; off >>= 1) part += __shfl_down(part, off, 64);
  if ((tid & 63) == 0) red[tid >> 6] = part;
  __syncthreads();
  if (tid == 0) {
    float tot = red[0] + red[1] + red[2] + red[3] + lb[0];
    float pq = 1.f / (1.f + expf(-tot));
    float pr = 0.5f * (probs_conv[b] + pq);
    out[b * 2 + 0] = pr;
    out[b * 2 + 1] = 1.f - pr;
  }
}

// ---------------- launch ----------------
extern "C" void kernel_launch(void* const* d_in, const int* in_sizes, int n_in,
                              void* d_out, int out_size, void* d_ws, size_t ws_size,
                              hipStream_t stream) {
  const float* x   = (const float*)d_in[0];
  const float* c1w = (const float*)d_in[1];
  const float* c1b = (const float*)d_in[2];
  const float* c2w = (const float*)d_in[3];
  const float* c2b = (const float*)d_in[4];
  const float* f1w = (const float*)d_in[5];
  const float* f1b = (const float*)d_in[6];
  const float* f2w = (const float*)d_in[7];
  const float* f2b = (const float*)d_in[8];
  const float* f3w = (const float*)d_in[9];
  const float* f3b = (const float*)d_in[10];
  const float* hth = (const float*)d_in[11];
  const float* qth = (const float*)d_in[12];
  const float* lw  = (const float*)d_in[13];
  const float* lb  = (const float*)d_in[14];
  float* out = (float*)d_out;
  char* ws = (char*)d_ws;

  float* pool1   = (float*)(ws);
  float* partial = pool1;  // pool1 dead after k_conv2
  float* h       = (float*)(ws + 46476288);
  float* tmp     = (float*)(ws + 75053568);
  float* fc1o    = (float*)(ws + 78623232);
  float* pconv   = (float*)(ws + 78684672);

  k_conv1<<<dim3(8, 3, 128), 256, 0, stream>>>(x, c1w, c1b, pool1);
  k_conv2<<<dim3(4, 4, 128), 256, 0, stream>>>(pool1, c2w, c2b, h);
  k_fc1<<<dim3(256), 256, 0, stream>>>(h, f1w, partial);
  k_fc1_reduce<<<dim3(60), 256, 0, stream>>>(partial, f1b, fc1o);
  k_head<<<dim3(128), 128, 0, stream>>>(fc1o, f2w, f2b, f3w, f3b, hth, pconv);
  k_resize_rows<<<dim3(128 * 28), 256, 0, stream>>>(x, tmp);
  k_quanv<<<dim3(128), 256, 0, stream>>>(tmp, qth, lw, lb, pconv, out);
}

// Round 8
// 387.612 us; speedup vs baseline: 1.4031x; 1.0763x over previous
//
#include <hip/hip_runtime.h>
#include <math.h>

#define DEV static __device__ __forceinline__

// ---------------- 4-qubit real-amplitude circuit helpers ----------------
template <int W>
DEV void q_ry(float s[16], float th) {
  float c = cosf(th * 0.5f), sn = sinf(th * 0.5f);
  constexpr int m = 8 >> W;
#pragma unroll
  for (int i = 0; i < 16; ++i) {
    if (!(i & m)) {
      float a = s[i], b = s[i | m];
      s[i] = c * a - sn * b;
      s[i | m] = sn * a + c * b;
    }
  }
}
template <int C, int T>
DEV void q_cnot(float s[16]) {
  constexpr int mc = 8 >> C, mt = 8 >> T;
#pragma unroll
  for (int i = 0; i < 16; ++i) {
    if ((i & mc) && !(i & mt)) {
      float t = s[i]; s[i] = s[i | mt]; s[i | mt] = t;
    }
  }
}
template <int W>
DEV float q_mz(const float s[16]) {
  constexpr int m = 8 >> W;
  float p = 0.f;
#pragma unroll
  for (int i = 0; i < 16; ++i) p += (i & m) ? -s[i] * s[i] : s[i] * s[i];
  return p;
}
DEV void q_layer(float s[16], const float* __restrict__ th) {
  q_ry<0>(s, th[0]); q_cnot<0, 1>(s);
  q_ry<1>(s, th[1]); q_cnot<1, 2>(s);
  q_ry<2>(s, th[2]); q_cnot<2, 3>(s);
  q_ry<3>(s, th[3]); q_cnot<3, 0>(s);
}

// ---------------- conv1 (5x5 s2 p1, 3->6) + relu + pool(2x2 s1) ----------------
// Strip-mined, 41x16 pooled tile, 252/256 threads. v4 changes:
//  - ct ALIASES xs (xs dead after conv; results live in regs) -> 38.7KB LDS
//    -> 4 blocks/CU (was 2).
//  - compute map co=tid%6, r=tid/6: groups of 6 lanes broadcast the same
//    xs row (was: every lane a distinct row -> 16-bank 4-way conflict).
//  - ct stride 19 (odd) -> all-bank coverage on write/pool phases.
// x: (128,3,249,249) -> pooled out: (128,6,123,123)
__global__ __launch_bounds__(256) void k_conv1(const float* __restrict__ x,
                                               const float* __restrict__ w,
                                               const float* __restrict__ bia,
                                               float* __restrict__ out) {
  __shared__ float smem[3 * 87 * 37];            // 9657 words = 38.7 KB
  float (*xs)[87][37] = (float (*)[87][37])smem; // staging view
  float (*ct)[42][19] = (float (*)[42][19])smem; // conv-subtile view (aliased)
  int b = blockIdx.z;
  int PY0 = blockIdx.y * 41, PX0 = blockIdx.x * 16;
  int iy0 = PY0 * 2 - 1, ix0 = PX0 * 2 - 1;
  int tid = threadIdx.x;
  const float* xb = x + (size_t)b * 186003;  // 3*249*249
  for (int idx = tid; idx < 3 * 87 * 37; idx += 256) {
    int ci = idx / 3219, rem = idx % 3219, rr = rem / 37, cc = rem % 37;
    int iy = iy0 + rr, ix = ix0 + cc;
    float v = 0.f;
    if (iy >= 0 && iy < 249 && ix >= 0 && ix < 249)
      v = xb[ci * 62001 + iy * 249 + ix];
    xs[ci][rr][cc] = v;
  }
  __syncthreads();
  int co = tid % 6, r = tid / 6;           // broadcast-friendly: 6 lanes/row
  float acc[17];
  if (tid < 252) {
    float bv = bia[co];
#pragma unroll
    for (int t = 0; t < 17; ++t) acc[t] = bv;
    for (int ci = 0; ci < 3; ++ci) {
      float wreg[25];                      // this co, this ci: 5x5
#pragma unroll
      for (int j = 0; j < 25; ++j) wreg[j] = w[co * 75 + ci * 25 + j];
#pragma unroll
      for (int ky = 0; ky < 5; ++ky) {
        const float* xrow = &xs[ci][2 * r + ky][0];
#pragma unroll
        for (int tx = 0; tx < 17; ++tx)
#pragma unroll
          for (int kx = 0; kx < 5; ++kx)
            acc[tx] += xrow[2 * tx + kx] * wreg[ky * 5 + kx];
      }
    }
  }
  __syncthreads();                         // all xs reads complete
  if (tid < 252) {
#pragma unroll
    for (int tx = 0; tx < 17; ++tx) ct[co][r][tx] = acc[tx];  // alias write
  }
  __syncthreads();
  if (tid < 246) {                         // 6 co * 41 pooled rows
    int co2 = tid % 6, pr = tid / 6;
    int py = PY0 + pr;                     // always < 123 (3*41=123)
    float* op = out + ((size_t)(b * 6 + co2) * 123 + py) * 123 + PX0;
#pragma unroll
    for (int pc = 0; pc < 16; ++pc) {
      if (PX0 + pc < 123) {
        float m = fmaxf(fmaxf(ct[co2][pr][pc], ct[co2][pr][pc + 1]),
                        fmaxf(ct[co2][pr + 1][pc], ct[co2][pr + 1][pc + 1]));
        op[pc] = fmaxf(m, 0.f);
      }
    }
  }
}

// ---------------- conv2 (3x3 s2 p1, 6->15) + relu + pool ----------------
// in: (128,6,123,123) -> h: (128, 15*61*61=55815) flattened
__global__ __launch_bounds__(256) void k_conv2(const float* __restrict__ in,
                                               const float* __restrict__ w,
                                               const float* __restrict__ bia,
                                               float* __restrict__ out) {
  __shared__ float xs[6][35][35];   // span = 16*2+3
  __shared__ float wt[54 * 15];     // transposed weights [j][co]
  __shared__ float ct[15][17][18];
  int b = blockIdx.z;
  int py0 = blockIdx.y * 16, px0 = blockIdx.x * 16;
  int iy0 = py0 * 2 - 1, ix0 = px0 * 2 - 1;
  int tid = threadIdx.x;
  for (int i = tid; i < 810; i += 256) {
    int j = i / 15, co = i % 15;
    wt[i] = w[co * 54 + j];
  }
  const float* ib = in + (size_t)b * 90774;  // 6*123*123
  for (int idx = tid; idx < 6 * 35 * 35; idx += 256) {
    int ci = idx / 1225, r = (idx % 1225) / 35, cc = idx % 35;
    int iy = iy0 + r, ix = ix0 + cc;
    float v = 0.f;
    if (iy >= 0 && iy < 123 && ix >= 0 && ix < 123)
      v = ib[ci * 15129 + iy * 123 + ix];
    xs[ci][r][cc] = v;
  }
  __syncthreads();
  if (tid < 255) {                 // 15 co * 17 rows
    int co = tid % 15, ty = tid / 15;
    float acc[17];
    float bv = bia[co];
#pragma unroll
    for (int t = 0; t < 17; ++t) acc[t] = bv;
#pragma unroll
    for (int ci = 0; ci < 6; ++ci)
#pragma unroll
      for (int ky = 0; ky < 3; ++ky) {
        int y = ty * 2 + ky;
        const int jb = (ci * 9 + ky * 3) * 15 + co;
        float w0 = wt[jb], w1 = wt[jb + 15], w2 = wt[jb + 30];
        float xp = xs[ci][y][0];
#pragma unroll
        for (int tx = 0; tx < 17; ++tx) {
          float xa = xs[ci][y][2 * tx + 1];
          float xb2 = xs[ci][y][2 * tx + 2];
          acc[tx] += xp * w0 + xa * w1 + xb2 * w2;
          xp = xb2;
        }
      }
#pragma unroll
    for (int tx = 0; tx < 17; ++tx) ct[co][ty][tx] = acc[tx];
  }
  __syncthreads();
  if (tid < 240) {                 // 15 co * 16 pooled rows
    int co = tid % 15, ty = tid / 15;
    int py = py0 + ty;
    if (py < 61) {
      float* op = out + (size_t)b * 55815 + co * 3721 + py * 61 + px0;
#pragma unroll
      for (int tx = 0; tx < 16; ++tx) {
        if (px0 + tx < 61) {
          float m = fmaxf(fmaxf(ct[co][ty][tx], ct[co][ty][tx + 1]),
                          fmaxf(ct[co][ty + 1][tx], ct[co][ty + 1][tx + 1]));
          op[tx] = fmaxf(m, 0.f);
        }
      }
    }
  }
}

// ---------------- fc1: (128,55815) x (120,55815)^T, split-K partials ----------------
#define KFC 55815
#define NCHUNK 1745  // ceil(55815/32)
__global__ __launch_bounds__(256) void k_fc1(const float* __restrict__ h,
                                             const float* __restrict__ w,
                                             float* __restrict__ partial) {
  __shared__ float hs[128][33];   // +1 pad
  __shared__ float wsd[120][33];
  int tid = threadIdx.x;
  int tb = tid & 31;   // batch lane
  int bo = tid >> 5;   // output group: outputs bo*15 .. bo*15+14
  float acc[4][15];
#pragma unroll
  for (int j = 0; j < 4; ++j)
#pragma unroll
    for (int oo = 0; oo < 15; ++oo) acc[j][oo] = 0.f;

  for (int ch = blockIdx.x; ch < NCHUNK; ch += gridDim.x) {
    int k0 = ch * 32;
    for (int idx = tid; idx < 128 * 32; idx += 256) {
      int bb = idx >> 5, kk = idx & 31;
      int k = k0 + kk;
      hs[bb][kk] = (k < KFC) ? h[(size_t)bb * KFC + k] : 0.f;
    }
    for (int idx = tid; idx < 120 * 32; idx += 256) {
      int oo = idx >> 5, kk = idx & 31;
      int k = k0 + kk;
      wsd[oo][kk] = (k < KFC) ? w[(size_t)oo * KFC + k] : 0.f;
    }
    __syncthreads();
#pragma unroll 4
    for (int kk = 0; kk < 32; ++kk) {
      float hv[4], wv[15];
#pragma unroll
      for (int j = 0; j < 4; ++j) hv[j] = hs[tb + 32 * j][kk];
#pragma unroll
      for (int oo = 0; oo < 15; ++oo) wv[oo] = wsd[bo * 15 + oo][kk];
#pragma unroll
      for (int j = 0; j < 4; ++j)
#pragma unroll
        for (int oo = 0; oo < 15; ++oo) acc[j][oo] += hv[j] * wv[oo];
    }
    __syncthreads();
  }
  float* pg = partial + (size_t)blockIdx.x * 15360;
#pragma unroll
  for (int j = 0; j < 4; ++j) {
    int b = tb + 32 * j;
#pragma unroll
    for (int oo = 0; oo < 15; ++oo) pg[b * 120 + bo * 15 + oo] = acc[j][oo];
  }
}

__global__ __launch_bounds__(256) void k_fc1_reduce(const float* __restrict__ partial,
                                                    const float* __restrict__ bias,
                                                    float* __restrict__ outv) {
  int i = blockIdx.x * 256 + threadIdx.x;
  if (i >= 15360) return;
  float a = bias[i % 120];
  for (int g = 0; g < 256; ++g) a += partial[(size_t)g * 15360 + i];
  outv[i] = fmaxf(a, 0.f);  // relu fused
}

// ---------------- fc2 + fc3 + quantum head -> probs_conv ----------------
__global__ __launch_bounds__(128) void k_head(const float* __restrict__ fc1o,
                                              const float* __restrict__ w2,
                                              const float* __restrict__ b2,
                                              const float* __restrict__ w3,
                                              const float* __restrict__ b3,
                                              const float* __restrict__ hth,
                                              float* __restrict__ probs_conv) {
  __shared__ float h1[120];
  __shared__ float h2[84];
  int b = blockIdx.x, tid = threadIdx.x;
  if (tid < 120) h1[tid] = fc1o[b * 120 + tid];  // already relu'd
  __syncthreads();
  if (tid < 84) {
    float a = b2[tid];
    for (int k = 0; k < 120; ++k) a += h1[k] * w2[tid * 120 + k];
    h2[tid] = fmaxf(a, 0.f);
  }
  __syncthreads();
  if (tid == 0) {
    float lg = b3[0];
    for (int j = 0; j < 84; ++j) lg += h2[j] * w3[j];
    float s[16];
#pragma unroll
    for (int i = 0; i < 16; ++i) s[i] = 0.f;
    s[0] = 1.f;
    q_ry<0>(s, lg);
    q_layer(s, hth);
    float z = q_mz<0>(s);
    probs_conv[b] = 1.f / (1.f + expf(-z));
  }
}

// ---------------- resize 249->28 (jax linear+antialias), row pass ----------------
DEV void resize_win(int o, int& i0, int& i1, float& sf, float& inorm) {
  const float invs = 249.0f / 28.0f;
  sf = ((float)o + 0.5f) * invs - 0.5f;
  i0 = (int)ceilf(sf - invs); if (i0 < 0) i0 = 0;
  i1 = (int)floorf(sf + invs); if (i1 > 248) i1 = 248;
  float nrm = 0.f;
  for (int i = i0; i <= i1; ++i)
    nrm += fmaxf(0.f, 1.f - fabsf(sf - (float)i) * (28.0f / 249.0f));
  inorm = 1.f / nrm;
}

// tmp[b][oy][ix] = sum_iy W[oy][iy] * gray[b][iy][ix]
__global__ __launch_bounds__(256) void k_resize_rows(const float* __restrict__ x,
                                                     float* __restrict__ tmp) {
  int b = blockIdx.x / 28, oy = blockIdx.x % 28;
  int ix = threadIdx.x;
  if (ix >= 249) return;
  int i0, i1; float sf, inorm;
  resize_win(oy, i0, i1, sf, inorm);
  const float* xb = x + (size_t)b * 186003;
  float acc = 0.f;
  for (int iy = i0; iy <= i1; ++iy) {
    float wv = fmaxf(0.f, 1.f - fabsf(sf - (float)iy) * (28.0f / 249.0f)) * inorm;
    float gr = (xb[iy * 249 + ix] + xb[62001 + iy * 249 + ix] +
                xb[124002 + iy * 249 + ix]) * (1.0f / 3.0f);
    acc += wv * gr;
  }
  tmp[((size_t)b * 28 + oy) * 249 + ix] = acc;
}

// ---------------- col pass + patches + per-patch circuits + lin + combine ----------------
__global__ __launch_bounds__(256) void k_quanv(const float* __restrict__ tmp,
                                               const float* __restrict__ qth,
                                               const float* __restrict__ lw,
                                               const float* __restrict__ lb,
                                               const float* __restrict__ probs_conv,
                                               float* __restrict__ out) {
  __shared__ float g[784];
  __shared__ float red[4];
  int b = blockIdx.x, tid = threadIdx.x;
  for (int idx = tid; idx < 784; idx += 256) {
    int oy = idx / 28, ox = idx % 28;
    int i0, i1; float sf, inorm;
    resize_win(ox, i0, i1, sf, inorm);
    const float* tr = tmp + ((size_t)b * 28 + oy) * 249;
    float acc = 0.f;
    for (int i = i0; i <= i1; ++i)
      acc += fmaxf(0.f, 1.f - fabsf(sf - (float)i) * (28.0f / 249.0f)) * inorm * tr[i];
    g[idx] = acc;
  }
  __syncthreads();
  float part = 0.f;
  if (tid < 196) {
    int pi = tid / 14, pj = tid % 14;
    float v0 = g[(2 * pi) * 28 + 2 * pj];
    float v1 = g[(2 * pi) * 28 + 2 * pj + 1];
    float v2 = g[(2 * pi + 1) * 28 + 2 * pj];
    float v3 = g[(2 * pi + 1) * 28 + 2 * pj + 1];
    float s[16];
#pragma unroll
    for (int i = 0; i < 16; ++i) s[i] = 0.f;
    s[0] = 1.f;
    q_ry<0>(s, v0); q_ry<1>(s, v1); q_ry<2>(s, v2); q_ry<3>(s, v3);
    q_layer(s, qth);
    float z0 = q_mz<0>(s), z1 = q_mz<1>(s), z2 = q_mz<2>(s), z3 = q_mz<3>(s);
    const float* lwp = lw + tid * 4;
    part = z0 * lwp[0] + z1 * lwp[1] + z2 * lwp[2] + z3 * lwp[3];
  }
#pragma unroll
  for (int off = 32; off > 0; off >>= 1) part += __shfl_down(part, off, 64);
  if ((tid & 63) == 0) red[tid >> 6] = part;
  __syncthreads();
  if (tid == 0) {
    float tot = red[0] + red[1] + red[2] + red[3] + lb[0];
    float pq = 1.f / (1.f + expf(-tot));
    float pr = 0.5f * (probs_conv[b] + pq);
    out[b * 2 + 0] = pr;
    out[b * 2 + 1] = 1.f - pr;
  }
}

// ---------------- launch ----------------
extern "C" void kernel_launch(void* const* d_in, const int* in_sizes, int n_in,
                              void* d_out, int out_size, void* d_ws, size_t ws_size,
                              hipStream_t stream) {
  const float* x   = (const float*)d_in[0];
  const float* c1w = (const float*)d_in[1];
  const float* c1b = (const float*)d_in[2];
  const float* c2w = (const float*)d_in[3];
  const float* c2b = (const float*)d_in[4];
  const float* f1w = (const float*)d_in[5];
  const float* f1b = (const float*)d_in[6];
  const float* f2w = (const float*)d_in[7];
  const float* f2b = (const float*)d_in[8];
  const float* f3w = (const float*)d_in[9];
  const float* f3b = (const float*)d_in[10];
  const float* hth = (const float*)d_in[11];
  const float* qth = (const float*)d_in[12];
  const float* lw  = (const float*)d_in[13];
  const float* lb  = (const float*)d_in[14];
  float* out = (float*)d_out;
  char* ws = (char*)d_ws;

  float* pool1   = (float*)(ws);
  float* partial = pool1;  // pool1 dead after k_conv2
  float* h       = (float*)(ws + 46476288);
  float* tmp     = (float*)(ws + 75053568);
  float* fc1o    = (float*)(ws + 78623232);
  float* pconv   = (float*)(ws + 78684672);

  k_conv1<<<dim3(8, 3, 128), 256, 0, stream>>>(x, c1w, c1b, pool1);
  k_conv2<<<dim3(4, 4, 128), 256, 0, stream>>>(pool1, c2w, c2b, h);
  k_fc1<<<dim3(256), 256, 0, stream>>>(h, f1w, partial);
  k_fc1_reduce<<<dim3(60), 256, 0, stream>>>(partial, f1b, fc1o);
  k_head<<<dim3(128), 128, 0, stream>>>(fc1o, f2w, f2b, f3w, f3b, hth, pconv);
  k_resize_rows<<<dim3(128 * 28), 256, 0, stream>>>(x, tmp);
  k_quanv<<<dim3(128), 256, 0, stream>>>(tmp, qth, lw, lb, pconv, out);
}

// Round 9
// 283.005 us; speedup vs baseline: 1.9218x; 1.3696x over previous
//
#include <hip/hip_runtime.h>
#include <math.h>

#define DEV static __device__ __forceinline__

// ---------------- 4-qubit real-amplitude circuit helpers ----------------
template <int W>
DEV void q_ry(float s[16], float th) {
  float c = cosf(th * 0.5f), sn = sinf(th * 0.5f);
  constexpr int m = 8 >> W;
#pragma unroll
  for (int i = 0; i < 16; ++i) {
    if (!(i & m)) {
      float a = s[i], b = s[i | m];
      s[i] = c * a - sn * b;
      s[i | m] = sn * a + c * b;
    }
  }
}
template <int C, int T>
DEV void q_cnot(float s[16]) {
  constexpr int mc = 8 >> C, mt = 8 >> T;
#pragma unroll
  for (int i = 0; i < 16; ++i) {
    if ((i & mc) && !(i & mt)) {
      float t = s[i]; s[i] = s[i | mt]; s[i | mt] = t;
    }
  }
}
template <int W>
DEV float q_mz(const float s[16]) {
  constexpr int m = 8 >> W;
  float p = 0.f;
#pragma unroll
  for (int i = 0; i < 16; ++i) p += (i & m) ? -s[i] * s[i] : s[i] * s[i];
  return p;
}
DEV void q_layer(float s[16], const float* __restrict__ th) {
  q_ry<0>(s, th[0]); q_cnot<0, 1>(s);
  q_ry<1>(s, th[1]); q_cnot<1, 2>(s);
  q_ry<2>(s, th[2]); q_cnot<2, 3>(s);
  q_ry<3>(s, th[3]); q_cnot<3, 0>(s);
}

// ---------------- conv1 (5x5 s2 p1, 3->6) + relu + pool(2x2 s1) ----------------
// v5: row stride 38 (8B-aligned) + float2 LDS reads (19 b64 / 85 FMA sweep,
// FMA becomes binding pipe); ct aliases xs; coalesced pooled stores.
// x: (128,3,249,249) -> pooled out: (128,6,123,123)
__global__ __launch_bounds__(256, 4) void k_conv1(const float* __restrict__ x,
                                                  const float* __restrict__ w,
                                                  const float* __restrict__ bia,
                                                  float* __restrict__ out) {
  __shared__ float smem[3 * 87 * 38];            // 9918 words = 39.7 KB
  float (*xs)[87][38] = (float (*)[87][38])smem; // staging view
  float (*ct)[42][19] = (float (*)[42][19])smem; // conv-subtile view (aliased)
  int b = blockIdx.z;
  int PY0 = blockIdx.y * 41, PX0 = blockIdx.x * 16;
  int iy0 = PY0 * 2 - 1, ix0 = PX0 * 2 - 1;
  int tid = threadIdx.x;
  const float* xb = x + (size_t)b * 186003;  // 3*249*249
  for (int idx = tid; idx < 3 * 87 * 38; idx += 256) {
    int ci = idx / 3306, rem = idx % 3306, rr = rem / 38, cc = rem % 38;
    int iy = iy0 + rr, ix = ix0 + cc;
    float v = 0.f;
    if (cc < 37 && iy >= 0 && iy < 249 && ix >= 0 && ix < 249)
      v = xb[ci * 62001 + iy * 249 + ix];
    xs[ci][rr][cc] = v;
  }
  __syncthreads();
  int co = tid % 6, r = tid / 6;           // 6 lanes/row -> broadcast reads
  float acc[17];
  if (tid < 252) {
    float bv = bia[co];
#pragma unroll
    for (int t = 0; t < 17; ++t) acc[t] = bv;
    for (int ci = 0; ci < 3; ++ci) {
      float wreg[25];                      // this co, this ci: 5x5
#pragma unroll
      for (int j = 0; j < 25; ++j) wreg[j] = w[co * 75 + ci * 25 + j];
#pragma unroll
      for (int ky = 0; ky < 5; ++ky) {
        const float* xrow = &xs[ci][2 * r + ky][0];  // 8B-aligned (stride 38)
        float xv[38];
#pragma unroll
        for (int j = 0; j < 19; ++j) {               // 19x ds_read_b64
          float2 t2 = *reinterpret_cast<const float2*>(&xrow[2 * j]);
          xv[2 * j] = t2.x; xv[2 * j + 1] = t2.y;
        }
#pragma unroll
        for (int tx = 0; tx < 17; ++tx)
#pragma unroll
          for (int kx = 0; kx < 5; ++kx)
            acc[tx] += xv[2 * tx + kx] * wreg[ky * 5 + kx];
      }
    }
  }
  __syncthreads();                         // all xs reads complete
  if (tid < 252) {
#pragma unroll
    for (int tx = 0; tx < 17; ++tx) ct[co][r][tx] = acc[tx];  // alias write
  }
  __syncthreads();
  // coalesced pool+store: 16 consecutive lanes = 16 consecutive cols (64B)
  for (int i = tid; i < 6 * 41 * 16; i += 256) {
    int co2 = i / 656, rem = i % 656, pr = rem / 16, pc = rem % 16;
    int py = PY0 + pr, px = PX0 + pc;
    if (px < 123) {
      float m = fmaxf(fmaxf(ct[co2][pr][pc], ct[co2][pr][pc + 1]),
                      fmaxf(ct[co2][pr + 1][pc], ct[co2][pr + 1][pc + 1]));
      out[((size_t)(b * 6 + co2) * 123 + py) * 123 + px] = fmaxf(m, 0.f);
    }
  }
}

// ---------------- conv2 (3x3 s2 p1, 6->15) + relu + pool ----------------
// v2: stride-36 rows + float2 LDS reads; weights in regs (9/ci); ct aliases xs;
// coalesced stores. in: (128,6,123,123) -> h: (128, 15*61*61=55815)
__global__ __launch_bounds__(256, 4) void k_conv2(const float* __restrict__ in,
                                                  const float* __restrict__ w,
                                                  const float* __restrict__ bia,
                                                  float* __restrict__ out) {
  __shared__ float smem[6 * 35 * 36];            // 7560 words = 30.2 KB
  float (*xs)[35][36] = (float (*)[35][36])smem; // staging view
  float (*ct)[17][18] = (float (*)[17][18])smem; // conv-subtile view (aliased)
  int b = blockIdx.z;
  int py0 = blockIdx.y * 16, px0 = blockIdx.x * 16;
  int iy0 = py0 * 2 - 1, ix0 = px0 * 2 - 1;
  int tid = threadIdx.x;
  const float* ib = in + (size_t)b * 90774;  // 6*123*123
  for (int idx = tid; idx < 6 * 35 * 36; idx += 256) {
    int ci = idx / 1260, rem = idx % 1260, rr = rem / 36, cc = rem % 36;
    int iy = iy0 + rr, ix = ix0 + cc;
    float v = 0.f;
    if (cc < 35 && iy >= 0 && iy < 123 && ix >= 0 && ix < 123)
      v = ib[ci * 15129 + iy * 123 + ix];
    xs[ci][rr][cc] = v;
  }
  __syncthreads();
  int co = tid % 15, ty = tid / 15;        // 15 lanes/row-group -> broadcast
  float acc[17];
  if (tid < 255) {
    float bv = bia[co];
#pragma unroll
    for (int t = 0; t < 17; ++t) acc[t] = bv;
#pragma unroll
    for (int ci = 0; ci < 6; ++ci) {
      float wreg[9];
#pragma unroll
      for (int j = 0; j < 9; ++j) wreg[j] = w[co * 54 + ci * 9 + j];
#pragma unroll
      for (int ky = 0; ky < 3; ++ky) {
        const float* xrow = &xs[ci][2 * ty + ky][0];  // 8B-aligned (stride 36)
        float xv[36];
#pragma unroll
        for (int j = 0; j < 18; ++j) {                // 18x ds_read_b64
          float2 t2 = *reinterpret_cast<const float2*>(&xrow[2 * j]);
          xv[2 * j] = t2.x; xv[2 * j + 1] = t2.y;
        }
#pragma unroll
        for (int tx = 0; tx < 17; ++tx)
#pragma unroll
          for (int kx = 0; kx < 3; ++kx)
            acc[tx] += xv[2 * tx + kx] * wreg[ky * 3 + kx];
      }
    }
  }
  __syncthreads();                         // all xs reads complete
  if (tid < 255) {
#pragma unroll
    for (int tx = 0; tx < 17; ++tx) ct[co][ty][tx] = acc[tx];  // alias write
  }
  __syncthreads();
  // coalesced pool+store
  for (int i = tid; i < 15 * 16 * 16; i += 256) {
    int co2 = i / 256, rem = i % 256, pr = rem / 16, pc = rem % 16;
    int py = py0 + pr, px = px0 + pc;
    if (py < 61 && px < 61) {
      float m = fmaxf(fmaxf(ct[co2][pr][pc], ct[co2][pr][pc + 1]),
                      fmaxf(ct[co2][pr + 1][pc], ct[co2][pr + 1][pc + 1]));
      out[(size_t)b * 55815 + co2 * 3721 + py * 61 + px] = fmaxf(m, 0.f);
    }
  }
}

// ---------------- fc1: (128,55815) x (120,55815)^T, split-K partials ----------------
#define KFC 55815
#define NCHUNK 1745  // ceil(55815/32)
#define FC1_BLOCKS 512
__global__ __launch_bounds__(256) void k_fc1(const float* __restrict__ h,
                                             const float* __restrict__ w,
                                             float* __restrict__ partial) {
  __shared__ float hs[128][33];   // +1 pad
  __shared__ float wsd[120][33];
  int tid = threadIdx.x;
  int tb = tid & 31;   // batch lane
  int bo = tid >> 5;   // output group: outputs bo*15 .. bo*15+14
  float acc[4][15];
#pragma unroll
  for (int j = 0; j < 4; ++j)
#pragma unroll
    for (int oo = 0; oo < 15; ++oo) acc[j][oo] = 0.f;

  for (int ch = blockIdx.x; ch < NCHUNK; ch += FC1_BLOCKS) {
    int k0 = ch * 32;
    for (int idx = tid; idx < 128 * 32; idx += 256) {
      int bb = idx >> 5, kk = idx & 31;
      int k = k0 + kk;
      hs[bb][kk] = (k < KFC) ? h[(size_t)bb * KFC + k] : 0.f;
    }
    for (int idx = tid; idx < 120 * 32; idx += 256) {
      int oo = idx >> 5, kk = idx & 31;
      int k = k0 + kk;
      wsd[oo][kk] = (k < KFC) ? w[(size_t)oo * KFC + k] : 0.f;
    }
    __syncthreads();
#pragma unroll 4
    for (int kk = 0; kk < 32; ++kk) {
      float hv[4], wv[15];
#pragma unroll
      for (int j = 0; j < 4; ++j) hv[j] = hs[tb + 32 * j][kk];
#pragma unroll
      for (int oo = 0; oo < 15; ++oo) wv[oo] = wsd[bo * 15 + oo][kk];
#pragma unroll
      for (int j = 0; j < 4; ++j)
#pragma unroll
        for (int oo = 0; oo < 15; ++oo) acc[j][oo] += hv[j] * wv[oo];
    }
    __syncthreads();
  }
  float* pg = partial + (size_t)blockIdx.x * 15360;
#pragma unroll
  for (int j = 0; j < 4; ++j) {
    int b = tb + 32 * j;
#pragma unroll
    for (int oo = 0; oo < 15; ++oo) pg[b * 120 + bo * 15 + oo] = acc[j][oo];
  }
}

__global__ __launch_bounds__(256) void k_fc1_reduce(const float* __restrict__ partial,
                                                    const float* __restrict__ bias,
                                                    float* __restrict__ outv) {
  int i = blockIdx.x * 256 + threadIdx.x;
  if (i >= 15360) return;
  float a = bias[i % 120];
  for (int g = 0; g < FC1_BLOCKS; ++g) a += partial[(size_t)g * 15360 + i];
  outv[i] = fmaxf(a, 0.f);  // relu fused
}

// ---------------- fc2 + fc3 + quantum head -> probs_conv ----------------
__global__ __launch_bounds__(128) void k_head(const float* __restrict__ fc1o,
                                              const float* __restrict__ w2,
                                              const float* __restrict__ b2,
                                              const float* __restrict__ w3,
                                              const float* __restrict__ b3,
                                              const float* __restrict__ hth,
                                              float* __restrict__ probs_conv) {
  __shared__ float h1[120];
  __shared__ float h2[84];
  int b = blockIdx.x, tid = threadIdx.x;
  if (tid < 120) h1[tid] = fc1o[b * 120 + tid];  // already relu'd
  __syncthreads();
  if (tid < 84) {
    float a = b2[tid];
    for (int k = 0; k < 120; ++k) a += h1[k] * w2[tid * 120 + k];
    h2[tid] = fmaxf(a, 0.f);
  }
  __syncthreads();
  if (tid == 0) {
    float lg = b3[0];
    for (int j = 0; j < 84; ++j) lg += h2[j] * w3[j];
    float s[16];
#pragma unroll
    for (int i = 0; i < 16; ++i) s[i] = 0.f;
    s[0] = 1.f;
    q_ry<0>(s, lg);
    q_layer(s, hth);
    float z = q_mz<0>(s);
    probs_conv[b] = 1.f / (1.f + expf(-z));
  }
}

// ---------------- resize 249->28 (jax linear+antialias), row pass ----------------
DEV void resize_win(int o, int& i0, int& i1, float& sf, float& inorm) {
  const float invs = 249.0f / 28.0f;
  sf = ((float)o + 0.5f) * invs - 0.5f;
  i0 = (int)ceilf(sf - invs); if (i0 < 0) i0 = 0;
  i1 = (int)floorf(sf + invs); if (i1 > 248) i1 = 248;
  float nrm = 0.f;
  for (int i = i0; i <= i1; ++i)
    nrm += fmaxf(0.f, 1.f - fabsf(sf - (float)i) * (28.0f / 249.0f));
  inorm = 1.f / nrm;
}

// tmp[b][oy][ix] = sum_iy W[oy][iy] * gray[b][iy][ix]
__global__ __launch_bounds__(256) void k_resize_rows(const float* __restrict__ x,
                                                     float* __restrict__ tmp) {
  int b = blockIdx.x / 28, oy = blockIdx.x % 28;
  int ix = threadIdx.x;
  if (ix >= 249) return;
  int i0, i1; float sf, inorm;
  resize_win(oy, i0, i1, sf, inorm);
  const float* xb = x + (size_t)b * 186003;
  float acc = 0.f;
  for (int iy = i0; iy <= i1; ++iy) {
    float wv = fmaxf(0.f, 1.f - fabsf(sf - (float)iy) * (28.0f / 249.0f)) * inorm;
    float gr = (xb[iy * 249 + ix] + xb[62001 + iy * 249 + ix] +
                xb[124002 + iy * 249 + ix]) * (1.0f / 3.0f);
    acc += wv * gr;
  }
  tmp[((size_t)b * 28 + oy) * 249 + ix] = acc;
}

// ---------------- col pass + patches + per-patch circuits + lin + combine ----------------
__global__ __launch_bounds__(256) void k_quanv(const float* __restrict__ tmp,
                                               const float* __restrict__ qth,
                                               const float* __restrict__ lw,
                                               const float* __restrict__ lb,
                                               const float* __restrict__ probs_conv,
                                               float* __restrict__ out) {
  __shared__ float g[784];
  __shared__ float red[4];
  int b = blockIdx.x, tid = threadIdx.x;
  for (int idx = tid; idx < 784; idx += 256) {
    int oy = idx / 28, ox = idx % 28;
    int i0, i1; float sf, inorm;
    resize_win(ox, i0, i1, sf, inorm);
    const float* tr = tmp + ((size_t)b * 28 + oy) * 249;
    float acc = 0.f;
    for (int i = i0; i <= i1; ++i)
      acc += fmaxf(0.f, 1.f - fabsf(sf - (float)i) * (28.0f / 249.0f)) * inorm * tr[i];
    g[idx] = acc;
  }
  __syncthreads();
  float part = 0.f;
  if (tid < 196) {
    int pi = tid / 14, pj = tid % 14;
    float v0 = g[(2 * pi) * 28 + 2 * pj];
    float v1 = g[(2 * pi) * 28 + 2 * pj + 1];
    float v2 = g[(2 * pi + 1) * 28 + 2 * pj];
    float v3 = g[(2 * pi + 1) * 28 + 2 * pj + 1];
    float s[16];
#pragma unroll
    for (int i = 0; i < 16; ++i) s[i] = 0.f;
    s[0] = 1.f;
    q_ry<0>(s, v0); q_ry<1>(s, v1); q_ry<2>(s, v2); q_ry<3>(s, v3);
    q_layer(s, qth);
    float z0 = q_mz<0>(s), z1 = q_mz<1>(s), z2 = q_mz<2>(s), z3 = q_mz<3>(s);
    const float* lwp = lw + tid * 4;
    part = z0 * lwp[0] + z1 * lwp[1] + z2 * lwp[2] + z3 * lwp[3];
  }
#pragma unroll
  for (int off = 32; off > 0; off >>= 1) part += __shfl_down(part, off, 64);
  if ((tid & 63) == 0) red[tid >> 6] = part;
  __syncthreads();
  if (tid == 0) {
    float tot = red[0] + red[1] + red[2] + red[3] + lb[0];
    float pq = 1.f / (1.f + expf(-tot));
    float pr = 0.5f * (probs_conv[b] + pq);
    out[b * 2 + 0] = pr;
    out[b * 2 + 1] = 1.f - pr;
  }
}

// ---------------- launch ----------------
extern "C" void kernel_launch(void* const* d_in, const int* in_sizes, int n_in,
                              void* d_out, int out_size, void* d_ws, size_t ws_size,
                              hipStream_t stream) {
  const float* x   = (const float*)d_in[0];
  const float* c1w = (const float*)d_in[1];
  const float* c1b = (const float*)d_in[2];
  const float* c2w = (const float*)d_in[3];
  const float* c2b = (const float*)d_in[4];
  const float* f1w = (const float*)d_in[5];
  const float* f1b = (const float*)d_in[6];
  const float* f2w = (const float*)d_in[7];
  const float* f2b = (const float*)d_in[8];
  const float* f3w = (const float*)d_in[9];
  const float* f3b = (const float*)d_in[10];
  const float* hth = (const float*)d_in[11];
  const float* qth = (const float*)d_in[12];
  const float* lw  = (const float*)d_in[13];
  const float* lb  = (const float*)d_in[14];
  float* out = (float*)d_out;
  char* ws = (char*)d_ws;

  float* pool1   = (float*)(ws);
  float* partial = pool1;  // pool1 dead after k_conv2; 512*15360*4 = 31.5MB < 46.4MB
  float* h       = (float*)(ws + 46476288);
  float* tmp     = (float*)(ws + 75053568);
  float* fc1o    = (float*)(ws + 78623232);
  float* pconv   = (float*)(ws + 78684672);

  k_conv1<<<dim3(8, 3, 128), 256, 0, stream>>>(x, c1w, c1b, pool1);
  k_conv2<<<dim3(4, 4, 128), 256, 0, stream>>>(pool1, c2w, c2b, h);
  k_fc1<<<dim3(FC1_BLOCKS), 256, 0, stream>>>(h, f1w, partial);
  k_fc1_reduce<<<dim3(60), 256, 0, stream>>>(partial, f1b, fc1o);
  k_head<<<dim3(128), 128, 0, stream>>>(fc1o, f2w, f2b, f3w, f3b, hth, pconv);
  k_resize_rows<<<dim3(128 * 28), 256, 0, stream>>>(x, tmp);
  k_quanv<<<dim3(128), 256, 0, stream>>>(tmp, qth, lw, lb, pconv, out);
}